// Round 11
// baseline (419.918 us; speedup 1.0000x reference)
//
#include <hip/hip_runtime.h>

#define NNODES 100000
#define NEDGES 1600000
#define FIN 128
#define FH 64
#define FOUT 32
#define NGRAPH 128
#define EPSV 1e-5f

#define SCAN_BT 256
#define NBLK ((NNODES + SCAN_BT - 1) / SCAN_BT)  // 391
#define GM ((NNODES + 63) / 64)                  // 1563 gemm blocks
#define FILLBLK 2048

typedef unsigned short ushort_t;
typedef __attribute__((ext_vector_type(8))) short bf16x8;
typedef __attribute__((ext_vector_type(4))) float f32x4;

// ---- bf16 helpers (RNE) ----
__device__ inline unsigned f2bf(float f) {
  union { float f; unsigned u; } x;
  x.f = f;
  return (x.u + 0x7fffu + ((x.u >> 16) & 1u)) >> 16;
}
__device__ inline float bflo(unsigned u) {
  union { unsigned u; float f; } x;
  x.u = u << 16;
  return x.f;
}
__device__ inline float bfhi(unsigned u) {
  union { unsigned u; float f; } x;
  x.u = u & 0xffff0000u;
  return x.f;
}

// ---------------- degree accumulation (XCD-partitioned) ----------------

__global__ void k_deg_accum(const int* __restrict__ dst, int* __restrict__ deg) {
  const int SLICE = NNODES / 8;
  int xcd = blockIdx.x & 7;
  int lo = xcd * SLICE, hi = lo + SLICE;
  int chunk = blockIdx.x >> 3;
  int nchunk = gridDim.x >> 3;
  for (int i = chunk * blockDim.x + threadIdx.x; i < NEDGES; i += nchunk * blockDim.x) {
    int d = dst[i];
    if (d >= lo && d < hi) atomicAdd(&deg[d], 1);
  }
}

// ---------------- CSR build: hierarchical exclusive scan ----------------

__global__ void k_blocksum(const int* __restrict__ deg, int* __restrict__ bsum) {
  __shared__ int ls[SCAN_BT];
  int b = blockIdx.x, t = threadIdx.x;
  int i = b * SCAN_BT + t;
  ls[t] = (i < NNODES) ? deg[i] : 0;
  __syncthreads();
  for (int s = SCAN_BT / 2; s > 0; s >>= 1) {
    if (t < s) ls[t] += ls[t + s];
    __syncthreads();
  }
  if (t == 0) bsum[b] = ls[0];
}

__global__ void k_scan_bsums(const int* __restrict__ bsum, int* __restrict__ boff) {
  __shared__ int ls[512];
  int t = threadIdx.x;
  int v = (t < NBLK) ? bsum[t] : 0;
  ls[t] = v;
  __syncthreads();
  for (int s = 1; s < 512; s <<= 1) {
    int add = (t >= s) ? ls[t - s] : 0;
    __syncthreads();
    ls[t] += add;
    __syncthreads();
  }
  if (t < NBLK) boff[t] = ls[t] - v;  // exclusive
}

__global__ void k_scan_final(const int* __restrict__ deg, const int* __restrict__ boff,
                             int* __restrict__ off, float* __restrict__ dis) {
  __shared__ int ls[SCAN_BT];
  int b = blockIdx.x, t = threadIdx.x;
  int i = b * SCAN_BT + t;
  int v = (i < NNODES) ? deg[i] : 0;
  ls[t] = v;
  __syncthreads();
  for (int s = 1; s < SCAN_BT; s <<= 1) {
    int add = (t >= s) ? ls[t - s] : 0;
    __syncthreads();
    ls[t] += add;
    __syncthreads();
  }
  if (i < NNODES) {
    off[i] = boff[b] + ls[t] - v;
    dis[i] = rsqrtf((float)v + 1.0f);  // self-loop folded in
  }
  if (i == NNODES - 1) off[NNODES] = boff[b] + ls[t];
}

// ---------------- MFMA GEMM body (shared by standalone + fused kernels) -----

template <int K, bool BN>
__device__ __forceinline__ void gemm_body(int bid, const float* __restrict__ A,
                                          const float* __restrict__ W,
                                          const float* __restrict__ stats,
                                          const float* __restrict__ gamma,
                                          const float* __restrict__ beta,
                                          const float* __restrict__ dis,
                                          ushort_t* __restrict__ out) {
  const int WT = K + 8;
  __shared__ ushort_t wt[64 * (K + 8)];
  __shared__ float bn_sc[K], bn_sh[K];
  if (BN && threadIdx.x < K) {
    int f = threadIdx.x;
    float mean = stats[f] * (1.0f / NNODES);
    float var = stats[K + f] * (1.0f / NNODES) - mean * mean;
    float s = gamma[f] * rsqrtf(var + EPSV);
    bn_sc[f] = s;
    bn_sh[f] = beta[f] - mean * s;  // bias b cancels in training-mode BN
  }
  for (int idx = threadIdx.x; idx < K * 64; idx += 256) {
    int k = idx >> 6, col = idx & 63;
    wt[col * WT + k] = (ushort_t)f2bf(W[idx]);
  }
  __syncthreads();

  int wave = threadIdx.x >> 6;
  int lane = threadIdx.x & 63;
  int rrow = lane & 15;
  int g = lane >> 4;
  int row0 = (bid * 4 + wave) * 16;
  int arow = min(row0 + rrow, NNODES - 1);
  const float* a = A + (long long)arow * K;

  f32x4 acc0 = {0.f, 0.f, 0.f, 0.f}, acc1 = acc0, acc2 = acc0, acc3 = acc0;

#pragma unroll
  for (int ks = 0; ks < K / 32; ++ks) {
    int koff = ks * 32 + g * 8;
    float4 xa = *(const float4*)(a + koff);
    float4 xb = *(const float4*)(a + koff + 4);
    float xs[8] = {xa.x, xa.y, xa.z, xa.w, xb.x, xb.y, xb.z, xb.w};
    if (BN) {
#pragma unroll
      for (int j = 0; j < 8; ++j)
        xs[j] = fmaxf(fmaf(xs[j], bn_sc[koff + j], bn_sh[koff + j]), 0.0f);
    }
    bf16x8 af;
#pragma unroll
    for (int j = 0; j < 8; ++j) af[j] = (short)f2bf(xs[j]);
    bf16x8 b0 = *(const bf16x8*)&wt[(0 * 16 + rrow) * WT + koff];
    bf16x8 b1 = *(const bf16x8*)&wt[(1 * 16 + rrow) * WT + koff];
    bf16x8 b2 = *(const bf16x8*)&wt[(2 * 16 + rrow) * WT + koff];
    bf16x8 b3 = *(const bf16x8*)&wt[(3 * 16 + rrow) * WT + koff];
    acc0 = __builtin_amdgcn_mfma_f32_16x16x32_bf16(af, b0, acc0, 0, 0, 0);
    acc1 = __builtin_amdgcn_mfma_f32_16x16x32_bf16(af, b1, acc1, 0, 0, 0);
    acc2 = __builtin_amdgcn_mfma_f32_16x16x32_bf16(af, b2, acc2, 0, 0, 0);
    acc3 = __builtin_amdgcn_mfma_f32_16x16x32_bf16(af, b3, acc3, 0, 0, 0);
  }

  int orow0 = row0 + g * 4;
#pragma unroll
  for (int r = 0; r < 4; ++r) {
    int orow = orow0 + r;
    if (orow < NNODES) {
      float d = dis[orow];
      ushort_t* o = out + (long long)orow * FH + rrow;
      o[0] = (ushort_t)f2bf(acc0[r] * d);
      o[16] = (ushort_t)f2bf(acc1[r] * d);
      o[32] = (ushort_t)f2bf(acc2[r] * d);
      o[48] = (ushort_t)f2bf(acc3[r] * d);
    }
  }
}

template <int K, bool BN>
__global__ void k_gemm_mfma(const float* __restrict__ A, const float* __restrict__ W,
                            const float* __restrict__ stats, const float* __restrict__ gamma,
                            const float* __restrict__ beta, const float* __restrict__ dis,
                            ushort_t* __restrict__ out) {
  gemm_body<K, BN>(blockIdx.x, A, W, stats, gamma, beta, dis, out);
}

// ---------------- fused: GEMM1 (blocks [0,GM)) || CSR fill (rest) -----------
// gemm1 is independent of the CSR build; fusing the grids lets them overlap
// on a single stream (saves gemm1's serial time).

__global__ void k_fill_gemm1(const float* __restrict__ x, const float* __restrict__ W1,
                             const float* __restrict__ dis, ushort_t* __restrict__ bufA,
                             const int* __restrict__ src, const int* __restrict__ dst,
                             const int* __restrict__ off, int* __restrict__ cursor,
                             int* __restrict__ csr) {
  if (blockIdx.x < GM) {
    gemm_body<FIN, false>(blockIdx.x, x, W1, nullptr, nullptr, nullptr, dis, bufA);
  } else {
    int bb = blockIdx.x - GM;
    const int SLICE = NNODES / 8;
    int xcd = bb & 7;
    int lo = xcd * SLICE, hi = lo + SLICE;
    int chunk = bb >> 3;
    int nchunk = FILLBLK >> 3;
    for (int i = chunk * blockDim.x + threadIdx.x; i < NEDGES; i += nchunk * blockDim.x) {
      int d = dst[i];
      if (d >= lo && d < hi) {
        int p = atomicAdd(&cursor[d], 1);
        csr[off[d] + p] = src[i];
      }
    }
  }
}

// ---------------- aggregation: out[d] = dis[d] * (hs[d] + sum hs[csr]) ------
// 8 groups x 8 lanes; each lane loads uint4 (8 bf16 feats) -> ONE instruction
// fetches 8 different rows (1KB). 2 nodes/wave, 16 slots/node/iter ->
// 4 csr + 4 row instructions per 32 edges (half of R9's count, same bytes in
// flight). Branchless tails via clamp+select; butterfly over lane bits 3,4,5.

#define ACC8(acc, u, ok)                       \
  acc[0] += (ok) ? bflo(u.x) : 0.0f;           \
  acc[1] += (ok) ? bfhi(u.x) : 0.0f;           \
  acc[2] += (ok) ? bflo(u.y) : 0.0f;           \
  acc[3] += (ok) ? bfhi(u.y) : 0.0f;           \
  acc[4] += (ok) ? bflo(u.z) : 0.0f;           \
  acc[5] += (ok) ? bfhi(u.z) : 0.0f;           \
  acc[6] += (ok) ? bflo(u.w) : 0.0f;           \
  acc[7] += (ok) ? bfhi(u.w) : 0.0f;

__global__ void k_gather(const ushort_t* __restrict__ hs, const int* __restrict__ csr,
                         const int* __restrict__ off, const float* __restrict__ dis,
                         float* __restrict__ out, float* __restrict__ stats) {
  __shared__ float ls[2 * FH];
  int tid = threadIdx.x;
  if (tid < 2 * FH) ls[tid] = 0.0f;
  __syncthreads();
  int lane = tid & 63;
  int q = lane >> 3;  // edge-slot group 0..7
  int i = lane & 7;   // feature octet: features [8i, 8i+7]
  int wid = (blockIdx.x * blockDim.x + tid) >> 6;
  int nw = (gridDim.x * blockDim.x) >> 6;
  const int HALF = NNODES / 2;
  float s1[8], s2[8];
#pragma unroll
  for (int f = 0; f < 8; ++f) s1[f] = s2[f] = 0.0f;

  for (int p = wid; p < HALF; p += nw) {
    int dA = p, dB = p + HALF;
    int bA = off[dA], eA = off[dA + 1];
    int bB = off[dB], eB = off[dB + 1];
    uint4 selfA = *(const uint4*)(hs + (long long)dA * FH + i * 8);
    uint4 selfB = *(const uint4*)(hs + (long long)dB * FH + i * 8);
    float accA[8], accB[8];
    bool q0 = (q == 0);
    ACC8(((float(&)[8])accA), selfA, q0);  // init-by-accumulate needs zeroed acc
#pragma unroll
    for (int f = 0; f < 8; ++f) accA[f] = q0 ? accA[f] : 0.0f;  // (see note below)
    // simpler correct init:
#pragma unroll
    for (int f = 0; f < 8; ++f) accA[f] = 0.0f;
#pragma unroll
    for (int f = 0; f < 8; ++f) accB[f] = 0.0f;
    ACC8(accA, selfA, q0);
    ACC8(accB, selfB, q0);

    int nA = (eA - bA + 15) >> 4, nB = (eB - bB + 15) >> 4;
    int niter = max(nA, nB);  // wave-uniform
    int lastA = max(eA - 1, 0), lastB = max(eB - 1, 0);
    int kA0 = bA + q, kA1 = bA + q + 8;
    int kB0 = bB + q, kB1 = bB + q + 8;
    for (int j = 0; j < niter; ++j) {
      int a0 = kA0 + 16 * j, a1 = kA1 + 16 * j;
      int b0 = kB0 + 16 * j, b1 = kB1 + 16 * j;
      int cA0 = csr[min(a0, lastA)];
      int cA1 = csr[min(a1, lastA)];
      int cB0 = csr[min(b0, lastB)];
      int cB1 = csr[min(b1, lastB)];
      uint4 uA0 = *(const uint4*)(hs + (long long)cA0 * FH + i * 8);
      uint4 uA1 = *(const uint4*)(hs + (long long)cA1 * FH + i * 8);
      uint4 uB0 = *(const uint4*)(hs + (long long)cB0 * FH + i * 8);
      uint4 uB1 = *(const uint4*)(hs + (long long)cB1 * FH + i * 8);
      bool A0 = a0 < eA, A1 = a1 < eA, B0 = b0 < eB, B1 = b1 < eB;
      ACC8(accA, uA0, A0);
      ACC8(accA, uA1, A1);
      ACC8(accB, uB0, B0);
      ACC8(accB, uB1, B1);
    }
    // butterfly across the 8 groups (lane bits 3,4,5)
#pragma unroll
    for (int f = 0; f < 8; ++f) {
      accA[f] += __shfl_xor(accA[f], 8);
      accA[f] += __shfl_xor(accA[f], 16);
      accA[f] += __shfl_xor(accA[f], 32);
      accB[f] += __shfl_xor(accB[f], 8);
      accB[f] += __shfl_xor(accB[f], 16);
      accB[f] += __shfl_xor(accB[f], 32);
    }
    float ddA = dis[dA], ddB = dis[dB];
#pragma unroll
    for (int f = 0; f < 8; ++f) {
      accA[f] *= ddA;
      accB[f] *= ddB;
      s1[f] += accA[f] + accB[f];
      s2[f] += accA[f] * accA[f] + accB[f] * accB[f];
    }
    if (q == 0) {
      float4 v0 = {accA[0], accA[1], accA[2], accA[3]};
      float4 v1 = {accA[4], accA[5], accA[6], accA[7]};
      *(float4*)(out + (long long)dA * FH + i * 8) = v0;
      *(float4*)(out + (long long)dA * FH + i * 8 + 4) = v1;
    } else if (q == 1) {
      float4 v0 = {accB[0], accB[1], accB[2], accB[3]};
      float4 v1 = {accB[4], accB[5], accB[6], accB[7]};
      *(float4*)(out + (long long)dB * FH + i * 8) = v0;
      *(float4*)(out + (long long)dB * FH + i * 8 + 4) = v1;
    }
  }
  if (q == 2) {  // one copy of the per-feature partial sums per wave
#pragma unroll
    for (int f = 0; f < 8; ++f) {
      atomicAdd(&ls[i * 8 + f], s1[f]);
      atomicAdd(&ls[FH + i * 8 + f], s2[f]);
    }
  }
  __syncthreads();
  if (tid < 2 * FH) atomicAdd(&stats[tid], ls[tid]);
}

// ---------------- pooling (BN2+ReLU fused; sc/sh computed per-lane) ---------

#define POOL_WAVES 1024

__global__ void k_pool(const float* __restrict__ h, const int* __restrict__ batch,
                       const float* __restrict__ stats, const float* __restrict__ gamma,
                       const float* __restrict__ beta, float* __restrict__ pooled,
                       float* __restrict__ cnt) {
  const int CHUNK = (NNODES + POOL_WAVES - 1) / POOL_WAVES;
  int lane = threadIdx.x & 63;
  int wid = (blockIdx.x * blockDim.x + threadIdx.x) >> 6;
  int start = wid * CHUNK;
  if (start >= NNODES) return;
  int end = min(start + CHUNK, NNODES);
  float mean = stats[lane] * (1.0f / NNODES);
  float var = stats[FH + lane] * (1.0f / NNODES) - mean * mean;
  float sc = gamma[lane] * rsqrtf(var + EPSV);
  float sh = beta[lane] - mean * sc;
  int cur = batch[start];
  float acc = 0.0f;
  int cl = 0;
  for (int n = start; n < end; ++n) {
    int g = batch[n];
    if (g != cur) {
      atomicAdd(&pooled[cur * FH + lane], acc);
      if (lane == 0) atomicAdd(&cnt[cur], (float)cl);
      acc = 0.0f;
      cl = 0;
      cur = g;
    }
    float v = fmaf(h[(long long)n * FH + lane], sc, sh);
    acc += fmaxf(v, 0.0f);
    ++cl;
  }
  atomicAdd(&pooled[cur * FH + lane], acc);
  if (lane == 0) atomicAdd(&cnt[cur], (float)cl);
}

// ---------------- final linear ----------------

__global__ void k_final(const float* __restrict__ pooled, const float* __restrict__ cnt,
                        const float* __restrict__ linW, const float* __restrict__ linb,
                        float* __restrict__ out) {
  int t = blockIdx.x * blockDim.x + threadIdx.x;
  if (t >= NGRAPH * FOUT) return;
  int g = t / FOUT, o = t % FOUT;
  float inv = 1.0f / fmaxf(cnt[g], 1.0f);
  float acc = linb[o];
#pragma unroll
  for (int k = 0; k < FH; ++k) acc = fmaf(pooled[g * FH + k] * inv, linW[k * FOUT + o], acc);
  out[t] = acc;
}

extern "C" void kernel_launch(void* const* d_in, const int* in_sizes, int n_in,
                              void* d_out, int out_size, void* d_ws, size_t ws_size,
                              hipStream_t stream) {
  const float* x = (const float*)d_in[0];
  const int* edge_index = (const int*)d_in[1];
  const int* batch = (const int*)d_in[2];
  const float* W1 = (const float*)d_in[3];
  // d_in[4] = b1 (cancels in BN), d_in[6] = b2 (cancels in BN)
  const float* W2 = (const float*)d_in[5];
  const float* gamma = (const float*)d_in[7];
  const float* beta = (const float*)d_in[8];
  const float* linW = (const float*)d_in[9];
  const float* linb = (const float*)d_in[10];
  float* out = (float*)d_out;

  const int* esrc = edge_index;
  const int* edst = edge_index + NEDGES;

  // workspace layout (bufA region float-sized; used as bf16)
  ushort_t* bufA = (ushort_t*)d_ws;                        // N*64 bf16
  float* bufB = (float*)d_ws + (long long)NNODES * FH;     // N*64 fp32
  float* dis = bufB + (long long)NNODES * FH;              // N
  int* off = (int*)(dis + NNODES);                         // N+1
  int* csr = off + (NNODES + 1);                           // E
  int* bsum = csr + NEDGES;                                // NBLK
  int* boff = bsum + NBLK;                                 // NBLK
  int* deg = boff + NBLK;                                  // N   --- zeroed region start
  int* cursor = deg + NNODES;                              // N
  float* stats1 = (float*)(cursor + NNODES);               // 128
  float* stats2 = stats1 + 2 * FH;                         // 128
  float* pooled = stats2 + 2 * FH;                         // G*64
  float* cnt = pooled + NGRAPH * FH;                       // G   --- zeroed region end

  const int BT = 256;

  hipMemsetAsync(deg, 0,
                 (size_t)(2 * NNODES + 2 * 2 * FH + NGRAPH * FH + NGRAPH) * sizeof(int), stream);

  // CSR pipeline; gemm1 fused into the fill launch (independent work overlaps)
  k_deg_accum<<<2048, BT, 0, stream>>>(edst, deg);
  k_blocksum<<<NBLK, SCAN_BT, 0, stream>>>(deg, bsum);
  k_scan_bsums<<<1, 512, 0, stream>>>(bsum, boff);
  k_scan_final<<<NBLK, SCAN_BT, 0, stream>>>(deg, boff, off, dis);
  k_fill_gemm1<<<GM + FILLBLK, BT, 0, stream>>>(x, W1, dis, bufA, esrc, edst, off, cursor, csr);

  // layer 1 aggregation
  k_gather<<<2048, BT, 0, stream>>>(bufA, csr, off, dis, bufB, stats1);

  // layer 2 (BN1 finalize+apply+ReLU fused into GEMM)
  k_gemm_mfma<FH, true><<<GM, BT, 0, stream>>>(bufB, W2, stats1, gamma, beta, dis, bufA);
  k_gather<<<2048, BT, 0, stream>>>(bufA, csr, off, dis, bufB, stats2);

  // pooling (BN2 fused) + final linear
  k_pool<<<POOL_WAVES * 64 / BT, BT, 0, stream>>>(bufB, batch, stats2, gamma, beta, pooled, cnt);
  k_final<<<(NGRAPH * FOUT + BT - 1) / BT, BT, 0, stream>>>(pooled, cnt, linW, linb, out);
}